// Round 4
// baseline (932.448 us; speedup 1.0000x reference)
//
#include <hip/hip_runtime.h>
#include <math.h>

// Problem constants
#define KCL    8192      // clusters
#define DIM    64        // embedding dim
#define NPTS   32768     // B*H*W
#define HW     1024      // H*W
#define PLANE  65536     // D*H*W (per-batch stride in z)
#define SPLITS 8
#define CBLK   (KCL / SPLITS)   // 1024 clusters per split

// -------------------- e2[k] = ||embedding[k]||^2 --------------------
__global__ __launch_bounds__(256) void e2_kernel(const float* __restrict__ emb,
                                                 float* __restrict__ e2) {
    int k = blockIdx.x * 256 + threadIdx.x;
    const float4* row = (const float4*)(emb + (size_t)k * DIM);
    float s = 0.f;
#pragma unroll
    for (int i = 0; i < DIM / 4; ++i) {
        float4 v = row[i];
        s += v.x * v.x + v.y * v.y + v.z * v.z + v.w * v.w;
    }
    e2[k] = s;
}

// -------------------- distance + argmin (no LDS) --------------------
// lane = point (z row in 64 VGPRs, loaded once, coalesced across lanes).
// cluster loop k is wave-uniform -> emb[k][*] and e2[k] become s_load
// (scalar pipe); inner loop = 64 x v_fmac_f32 acc, s_e, v_z.
// K split 8 ways across blocks; partial (best,k) written to scratch.
__global__ __launch_bounds__(256) void vq_dist(
    const float* __restrict__ z, const float* __restrict__ emb,
    const float* __restrict__ e2g, float* __restrict__ bestO,
    int* __restrict__ kbestO) {
    const int t  = threadIdx.x;
    const int ks = blockIdx.x & (SPLITS - 1);   // same split clusters on same XCD
    const int pb = blockIdx.x >> 3;
    const int p  = (pb << 8) + t;               // global point
    const int b  = p >> 10, hw = p & 1023;
    const float* zp = z + (size_t)b * PLANE + hw;

    float zv[DIM];
#pragma unroll
    for (int d = 0; d < DIM; ++d) zv[d] = zp[(size_t)d * HW];

    float best = 3.4e38f;
    int   bk   = 0;
    const int k0 = ks * CBLK;
    for (int k = k0; k < k0 + CBLK; ++k) {
        const float* __restrict__ er = emb + ((size_t)k << 6);
        float acc = 0.f;
#pragma unroll
        for (int d = 0; d < DIM; ++d) acc = fmaf(er[d], zv[d], acc);
        float dist = fmaf(-2.f, acc, e2g[k]);
        if (dist < best) { best = dist; bk = k; }   // strict < : first-index ties
    }
    bestO[ks * NPTS + p]  = best;
    kbestO[ks * NPTS + p] = bk;
}

// -------------------- merge splits + epilogue --------------------
// Ascending split order + strict < == exact global first-index argmin.
__global__ __launch_bounds__(256) void merge_epi(
    const float* __restrict__ z, const float* __restrict__ emb,
    const float* __restrict__ bestO, const int* __restrict__ kbestO,
    float* __restrict__ counts, float* __restrict__ bavg,
    float* __restrict__ loss_ws, float* __restrict__ zq_out,
    float* __restrict__ idx_out) {
    const int t = threadIdx.x;
    const int p = blockIdx.x * 256 + t;
    float best = 3.4e38f;
    int   bk   = 0;
#pragma unroll
    for (int s = 0; s < SPLITS; ++s) {
        float d = bestO[s * NPTS + p];
        int   k = kbestO[s * NPTS + p];
        if (d < best) { best = d; bk = k; }
    }
    idx_out[p] = (float)bk;
    atomicAdd(&counts[bk], 1.0f);

    const int b = p >> 10, hw = p & 1023;
    const float* er = emb + ((size_t)bk << 6);
    float lsum = 0.f;
#pragma unroll
    for (int d = 0; d < DIM; ++d) {
        size_t g  = (size_t)b * PLANE + (size_t)d * HW + hw;
        float zvv = z[g];
        float ev  = er[d];
        zq_out[g] = ev;                        // coalesced across lanes
        float df  = ev - zvv;
        lsum = fmaf(df, df, lsum);
        atomicAdd(&bavg[((size_t)bk << 6) + d], zvv);
    }
#pragma unroll
    for (int off = 32; off > 0; off >>= 1) lsum += __shfl_xor(lsum, off);
    if ((t & 63) == 0) atomicAdd(loss_ws, lsum);
}

// -------------------- EMA finalize: outputs 4,5,6 --------------------
__global__ __launch_bounds__(256) void ema_kernel(
    const float* __restrict__ ema_cs, const float* __restrict__ ema_avg,
    const float* __restrict__ counts, const float* __restrict__ bavg,
    float* __restrict__ out_ncs, float* __restrict__ out_navg,
    float* __restrict__ out_nemb) {
    int tid = blockIdx.x * 256 + threadIdx.x;  // 0..131071 (K*D/4)
    int k = tid >> 4;
    float ncs = 0.99f * ema_cs[k] + 0.01f * counts[k];
    float den = ncs + 1e-5f;
    float4 ea = ((const float4*)ema_avg)[tid];
    float4 ba = ((const float4*)bavg)[tid];
    float4 na, ne;
    na.x = 0.99f * ea.x + 0.01f * ba.x;
    na.y = 0.99f * ea.y + 0.01f * ba.y;
    na.z = 0.99f * ea.z + 0.01f * ba.z;
    na.w = 0.99f * ea.w + 0.01f * ba.w;
    ne.x = na.x / den; ne.y = na.y / den; ne.z = na.z / den; ne.w = na.w / den;
    ((float4*)out_navg)[tid] = na;
    ((float4*)out_nemb)[tid] = ne;
    if ((tid & 15) == 0) out_ncs[k] = ncs;
}

// -------------------- scalars: loss + perplexity --------------------
__global__ __launch_bounds__(256) void scalars_kernel(
    const float* __restrict__ counts, const float* __restrict__ loss_ws,
    float* __restrict__ out_loss, float* __restrict__ out_perp) {
    __shared__ float red[4];
    float s = 0.f;
    for (int k = threadIdx.x; k < KCL; k += 256) {
        float p = counts[k] * (1.0f / (float)NPTS);
        s += p * logf(p + 1e-10f);
    }
#pragma unroll
    for (int off = 32; off > 0; off >>= 1) s += __shfl_xor(s, off, 64);
    if ((threadIdx.x & 63) == 0) red[threadIdx.x >> 6] = s;
    __syncthreads();
    if (threadIdx.x == 0) {
        float tot = red[0] + red[1] + red[2] + red[3];
        out_perp[0] = expf(-tot);
        out_loss[0] = 0.25f * loss_ws[0] / (float)(NPTS * DIM);
    }
}

extern "C" void kernel_launch(void* const* d_in, const int* in_sizes, int n_in,
                              void* d_out, int out_size, void* d_ws, size_t ws_size,
                              hipStream_t stream) {
    (void)in_sizes; (void)n_in; (void)out_size; (void)ws_size;
    const float* z       = (const float*)d_in[0];
    const float* emb     = (const float*)d_in[1];
    const float* ema_cs  = (const float*)d_in[2];
    const float* ema_avg = (const float*)d_in[3];

    float* out0      = (float*)d_out;            // z_quantized_st  [2097152]
    float* out_loss  = out0 + 2097152;           // loss            [1]
    float* out_perp  = out_loss + 1;             // perplexity      [1]
    float* out_idx   = out_perp + 1;             // encoding_indices[32768]
    float* out_nemb  = out_idx + NPTS;           // new_embedding   [524288]
    float* out_ncs   = out_nemb + KCL * DIM;     // new_cluster_size[8192]
    float* out_navg  = out_ncs + KCL;            // new_embedding_avg[524288]

    float* e2_ws     = (float*)d_ws;             // [8192]
    float* counts_ws = e2_ws + KCL;              // [8192]
    float* bavg_ws   = counts_ws + KCL;          // [524288]
    float* loss_ws   = bavg_ws + KCL * DIM;      // [1]

    // split-argmin scratch overlaid on the new_embedding output region
    // (524288 floats; ema_kernel rewrites it AFTER merge_epi consumed it)
    float* bestO  = out_nemb;                    // [SPLITS*NPTS] = 262144
    int*   kbestO = (int*)(out_nemb + SPLITS * NPTS);  // [262144]

    // zero the accumulators (counts + bavg + loss scalar)
    hipMemsetAsync((void*)counts_ws, 0, (size_t)(KCL + KCL * DIM + 1) * sizeof(float), stream);

    e2_kernel<<<KCL / 256, 256, 0, stream>>>(emb, e2_ws);
    vq_dist<<<(NPTS / 256) * SPLITS, 256, 0, stream>>>(z, emb, e2_ws, bestO, kbestO);
    merge_epi<<<NPTS / 256, 256, 0, stream>>>(z, emb, bestO, kbestO, counts_ws,
                                              bavg_ws, loss_ws, out0, out_idx);
    ema_kernel<<<KCL * DIM / 4 / 256, 256, 0, stream>>>(ema_cs, ema_avg, counts_ws,
                                                        bavg_ws, out_ncs, out_navg, out_nemb);
    scalars_kernel<<<1, 256, 0, stream>>>(counts_ws, loss_ws, out_loss, out_perp);
}